// Round 1
// baseline (290.633 us; speedup 1.0000x reference)
//
#include <hip/hip_runtime.h>
#include <hip/hip_bf16.h>
#include <math.h>

#define EMB 128
#define HID 128
#define NCOL 256   // src-proj(128) ++ dst-proj(128)

// ---------------------------------------------------------------------------
// Kernel 1: per-node projection  P[n][0:128]  = x_n @ W1[0:128]
//                                P[n][128:256]= x_n @ W1[128:256]
// M=N_nodes, K=128, N=256 fp32 GEMM. 64 nodes x 256 cols per block,
// BK=16 LDS chunks, 256 threads, 4x16 micro-tile per thread.
// ---------------------------------------------------------------------------
__global__ __launch_bounds__(256) void proj_kernel(
    const float* __restrict__ A,    // [N][128] node_emb
    const float* __restrict__ W1,   // [256][128]
    float* __restrict__ P,          // [N][256]
    int N)
{
    __shared__ float sW[16][NCOL];  // 16 KB  [k][col]
    __shared__ float sA[16][64];    // 4 KB   [k][node] (transposed)

    const int tid = threadIdx.x;
    const int tx  = tid & 15;       // col group 0..15
    const int ty  = tid >> 4;       // node group 0..15
    const int m0  = blockIdx.x * 64;

    float acc[4][16];
#pragma unroll
    for (int i = 0; i < 4; ++i)
#pragma unroll
        for (int j = 0; j < 16; ++j) acc[i][j] = 0.0f;

    for (int k0 = 0; k0 < EMB; k0 += 16) {
        __syncthreads();
        // ---- stage W chunk: rows k0..k0+15 of combined [128][256] weight ----
#pragma unroll
        for (int i = 0; i < 4; ++i) {
            int fid = tid + 256 * i;          // 0..1023 float4 id
            int kk  = fid >> 6;               // 0..15
            int c4  = (fid & 63) * 4;         // 0..252
            int k   = k0 + kk;
            const float* src = (c4 < HID)
                ? (W1 + (size_t)k * HID + c4)
                : (W1 + (size_t)(EMB + k) * HID + (c4 - HID));
            float4 v = *(const float4*)src;
            *(float4*)&sW[kk][c4] = v;
        }
        // ---- stage A chunk (transposed): 1 float4 per thread ----
        {
            int nn   = tid >> 2;              // 0..63
            int kk4  = (tid & 3) * 4;         // 0,4,8,12
            int node = m0 + nn;
            int nc   = node < N ? node : N - 1;
            float4 v = *(const float4*)&A[(size_t)nc * EMB + k0 + kk4];
            sA[kk4 + 0][nn] = v.x;
            sA[kk4 + 1][nn] = v.y;
            sA[kk4 + 2][nn] = v.z;
            sA[kk4 + 3][nn] = v.w;
        }
        __syncthreads();
        // ---- compute ----
#pragma unroll
        for (int k = 0; k < 16; ++k) {
            float4 a = *(const float4*)&sA[k][ty * 4];
            float av[4] = {a.x, a.y, a.z, a.w};
#pragma unroll
            for (int q = 0; q < 4; ++q) {
                float4 w = *(const float4*)&sW[k][tx * 4 + q * 64];
#pragma unroll
                for (int i = 0; i < 4; ++i) {
                    acc[i][q * 4 + 0] = fmaf(av[i], w.x, acc[i][q * 4 + 0]);
                    acc[i][q * 4 + 1] = fmaf(av[i], w.y, acc[i][q * 4 + 1]);
                    acc[i][q * 4 + 2] = fmaf(av[i], w.z, acc[i][q * 4 + 2]);
                    acc[i][q * 4 + 3] = fmaf(av[i], w.w, acc[i][q * 4 + 3]);
                }
            }
        }
    }
    // ---- epilogue ----
#pragma unroll
    for (int i = 0; i < 4; ++i) {
        int node = m0 + ty * 4 + i;
        if (node < N) {
#pragma unroll
            for (int q = 0; q < 4; ++q) {
                float4 v = make_float4(acc[i][q * 4 + 0], acc[i][q * 4 + 1],
                                       acc[i][q * 4 + 2], acc[i][q * 4 + 3]);
                *(float4*)&P[(size_t)node * NCOL + tx * 4 + q * 64] = v;
            }
        }
    }
}

// ---------------------------------------------------------------------------
// Kernel 2: per-edge: h = P[src][0:128] + P[dst][128:256] + b1 ; LayerNorm ;
//           ReLU ; sigmoid(h @ W2 + b2). 32 lanes per edge, float4 per lane.
// ---------------------------------------------------------------------------
__global__ __launch_bounds__(256) void edge_kernel(
    const float* __restrict__ P,
    const int* __restrict__ ei,     // [2][E]
    const float* __restrict__ b1,
    const float* __restrict__ lng,
    const float* __restrict__ lnb,
    const float* __restrict__ W2,
    const float* __restrict__ b2,
    float* __restrict__ out, int E)
{
    const int lane = threadIdx.x & 31;
    const int c0   = lane * 4;
    const float4 vb1 = *(const float4*)(b1  + c0);
    const float4 vg  = *(const float4*)(lng + c0);
    const float4 vbt = *(const float4*)(lnb + c0);
    const float4 vw2 = *(const float4*)(W2  + c0);
    const float bias2 = b2[0];

    int slot   = blockIdx.x * (blockDim.x >> 5) + (threadIdx.x >> 5);
    int nslots = gridDim.x * (blockDim.x >> 5);

    for (int e = slot; e < E; e += nslots) {
        int src = ei[e];
        int dst = ei[E + e];
        const float4 p0 = *(const float4*)(P + (size_t)src * NCOL + c0);
        const float4 p1 = *(const float4*)(P + (size_t)dst * NCOL + HID + c0);
        float h0 = p0.x + p1.x + vb1.x;
        float h1 = p0.y + p1.y + vb1.y;
        float h2 = p0.z + p1.z + vb1.z;
        float h3 = p0.w + p1.w + vb1.w;

        float s  = h0 + h1 + h2 + h3;
        float sq = h0 * h0 + h1 * h1 + h2 * h2 + h3 * h3;
#pragma unroll
        for (int m = 16; m >= 1; m >>= 1) {
            s  += __shfl_xor(s,  m, 32);
            sq += __shfl_xor(sq, m, 32);
        }
        float mu  = s * (1.0f / HID);
        float var = sq * (1.0f / HID) - mu * mu;
        float r   = rsqrtf(var + 1e-5f);

        float y0 = fmaxf(fmaf((h0 - mu) * r, vg.x, vbt.x), 0.0f);
        float y1 = fmaxf(fmaf((h1 - mu) * r, vg.y, vbt.y), 0.0f);
        float y2 = fmaxf(fmaf((h2 - mu) * r, vg.z, vbt.z), 0.0f);
        float y3 = fmaxf(fmaf((h3 - mu) * r, vg.w, vbt.w), 0.0f);

        float z = y0 * vw2.x + y1 * vw2.y + y2 * vw2.z + y3 * vw2.w;
#pragma unroll
        for (int m = 16; m >= 1; m >>= 1) z += __shfl_xor(z, m, 32);

        if (lane == 0) {
            float zz = z + bias2;
            float wv = 1.0f / (1.0f + expf(-zz));
            if (wv != wv) wv = 0.5f;   // nan_to_num(nan=0.5)
            out[e] = wv;
        }
    }
}

// ---------------------------------------------------------------------------
// Fallback (only if ws too small): fused per-edge matmul, slow but correct.
// ---------------------------------------------------------------------------
__global__ __launch_bounds__(256) void fused_kernel(
    const float* __restrict__ X,
    const int* __restrict__ ei,
    const float* __restrict__ W1,
    const float* __restrict__ b1,
    const float* __restrict__ lng,
    const float* __restrict__ lnb,
    const float* __restrict__ W2,
    const float* __restrict__ b2,
    float* __restrict__ out, int E)
{
    const int lane = threadIdx.x & 31;
    const int c0   = lane * 4;
    const float4 vb1 = *(const float4*)(b1  + c0);
    const float4 vg  = *(const float4*)(lng + c0);
    const float4 vbt = *(const float4*)(lnb + c0);
    const float4 vw2 = *(const float4*)(W2  + c0);
    const float bias2 = b2[0];

    int slot   = blockIdx.x * (blockDim.x >> 5) + (threadIdx.x >> 5);
    int nslots = gridDim.x * (blockDim.x >> 5);

    for (int e = slot; e < E; e += nslots) {
        int src = ei[e];
        int dst = ei[E + e];
        const float* xs = X + (size_t)src * EMB;
        const float* xd = X + (size_t)dst * EMB;
        float h0 = vb1.x, h1 = vb1.y, h2 = vb1.z, h3 = vb1.w;
        for (int k = 0; k < EMB; ++k) {
            float a  = xs[k];
            float4 w = *(const float4*)(W1 + (size_t)k * HID + c0);
            h0 = fmaf(a, w.x, h0); h1 = fmaf(a, w.y, h1);
            h2 = fmaf(a, w.z, h2); h3 = fmaf(a, w.w, h3);
        }
        for (int k = 0; k < EMB; ++k) {
            float a  = xd[k];
            float4 w = *(const float4*)(W1 + (size_t)(EMB + k) * HID + c0);
            h0 = fmaf(a, w.x, h0); h1 = fmaf(a, w.y, h1);
            h2 = fmaf(a, w.z, h2); h3 = fmaf(a, w.w, h3);
        }
        float s  = h0 + h1 + h2 + h3;
        float sq = h0 * h0 + h1 * h1 + h2 * h2 + h3 * h3;
#pragma unroll
        for (int m = 16; m >= 1; m >>= 1) {
            s  += __shfl_xor(s,  m, 32);
            sq += __shfl_xor(sq, m, 32);
        }
        float mu  = s * (1.0f / HID);
        float var = sq * (1.0f / HID) - mu * mu;
        float r   = rsqrtf(var + 1e-5f);
        float y0 = fmaxf(fmaf((h0 - mu) * r, vg.x, vbt.x), 0.0f);
        float y1 = fmaxf(fmaf((h1 - mu) * r, vg.y, vbt.y), 0.0f);
        float y2 = fmaxf(fmaf((h2 - mu) * r, vg.z, vbt.z), 0.0f);
        float y3 = fmaxf(fmaf((h3 - mu) * r, vg.w, vbt.w), 0.0f);
        float z = y0 * vw2.x + y1 * vw2.y + y2 * vw2.z + y3 * vw2.w;
#pragma unroll
        for (int m = 16; m >= 1; m >>= 1) z += __shfl_xor(z, m, 32);
        if (lane == 0) {
            float zz = z + bias2;
            float wv = 1.0f / (1.0f + expf(-zz));
            if (wv != wv) wv = 0.5f;
            out[e] = wv;
        }
    }
}

extern "C" void kernel_launch(void* const* d_in, const int* in_sizes, int n_in,
                              void* d_out, int out_size, void* d_ws, size_t ws_size,
                              hipStream_t stream) {
    const float* node_emb = (const float*)d_in[0];
    const int*   ei       = (const int*)d_in[1];
    const float* W1       = (const float*)d_in[2];
    const float* b1       = (const float*)d_in[3];
    const float* lng      = (const float*)d_in[4];
    const float* lnb      = (const float*)d_in[5];
    const float* W2       = (const float*)d_in[6];
    const float* b2       = (const float*)d_in[7];
    float* out = (float*)d_out;

    const int N = in_sizes[0] / EMB;   // 100000
    const int E = in_sizes[1] / 2;     // 800000

    const size_t need = (size_t)N * NCOL * sizeof(float);
    if (ws_size >= need) {
        float* P = (float*)d_ws;
        dim3 grid_p((N + 63) / 64);
        proj_kernel<<<grid_p, 256, 0, stream>>>(node_emb, W1, P, N);
        edge_kernel<<<2048, 256, 0, stream>>>(P, ei, b1, lng, lnb, W2, b2, out, E);
    } else {
        fused_kernel<<<2048, 256, 0, stream>>>(node_emb, ei, W1, b1, lng, lnb,
                                               W2, b2, out, E);
    }
}

// Round 2
// 204.147 us; speedup vs baseline: 1.4236x; 1.4236x over previous
//
#include <hip/hip_runtime.h>
#include <hip/hip_bf16.h>
#include <math.h>

#define EMB 128
#define HID 128
#define NCOL 256   // src-proj(128) ++ dst-proj(128)

typedef __attribute__((ext_vector_type(8))) short short8v;   // 8 bf16 = 4 VGPR
typedef __attribute__((ext_vector_type(4))) float f32x4;     // MFMA acc
typedef __attribute__((ext_vector_type(8))) unsigned short ushort8v;

__device__ __forceinline__ short f2bf(float f) {
    union { float f; unsigned int u; } v; v.f = f;
    unsigned int r = (v.u + 0x7FFFu + ((v.u >> 16) & 1u)) >> 16;
    return (short)r;
}
__device__ __forceinline__ float bf2f(unsigned short u) {
    return __uint_as_float(((unsigned int)u) << 16);
}

// ---------------------------------------------------------------------------
// Kernel 0: Wt[c][k] (bf16) = combined-W1 transposed:
//   c<128 : W1[k][c]      (src projection col c)
//   c>=128: W1[128+k][c-128] (dst projection col c-128)
// 32768 elements, trivial.
// ---------------------------------------------------------------------------
__global__ __launch_bounds__(256) void w_prep(
    const float* __restrict__ W1, unsigned short* __restrict__ Wt)
{
    int idx = blockIdx.x * 256 + threadIdx.x;      // 0..32767
    int c = idx >> 7;          // 0..255
    int k = idx & 127;         // 0..127
    float v = W1[(size_t)(k + ((c >> 7) << 7)) * HID + (c & 127)];
    Wt[idx] = (unsigned short)f2bf(v);
}

// ---------------------------------------------------------------------------
// Kernel 1: P[n][c] (bf16) = x_n @ B,  B[k][c] from Wt.  MFMA 16x16x32 bf16.
// Block = 4 waves; wave w owns cols 64w..64w+63 (4 col-frags), B-frags in
// registers for the whole block (16 frags x 16B, loaded once from L2).
// Grid-stride over M-tiles of 64 rows.
// ---------------------------------------------------------------------------
__global__ __launch_bounds__(256) void proj_mfma(
    const float* __restrict__ A,          // [N][128] f32
    const unsigned short* __restrict__ Wt,// [256][128] bf16
    unsigned short* __restrict__ P,       // [N][256] bf16
    int N, int nTiles)
{
    const int w    = threadIdx.x >> 6;    // wave 0..3
    const int lane = threadIdx.x & 63;
    const int l16  = lane & 15;
    const int lk   = lane >> 4;           // 0..3 (k-group)

    // B fragments: bfrag[cf][ks], col = 64w+16cf+l16, k = 32ks+8lk+i
    short8v bfrag[4][4];
#pragma unroll
    for (int cf = 0; cf < 4; ++cf)
#pragma unroll
        for (int ks = 0; ks < 4; ++ks) {
            int c = 64 * w + 16 * cf + l16;
            int k = 32 * ks + 8 * lk;
            bfrag[cf][ks] = *(const short8v*)(Wt + (size_t)c * EMB + k);
        }

    for (int t = blockIdx.x; t < nTiles; t += gridDim.x) {
        const int m0 = t * 64;
        f32x4 acc[4][4];
#pragma unroll
        for (int rf = 0; rf < 4; ++rf)
#pragma unroll
            for (int cf = 0; cf < 4; ++cf) acc[rf][cf] = (f32x4)0.0f;

#pragma unroll
        for (int ks = 0; ks < 4; ++ks) {
#pragma unroll
            for (int rf = 0; rf < 4; ++rf) {
                int row = m0 + 16 * rf + l16;
                row = row < N ? row : N - 1;
                const float* ap = A + (size_t)row * EMB + 32 * ks + 8 * lk;
                float4 a0 = *(const float4*)ap;
                float4 a1 = *(const float4*)(ap + 4);
                short8v af = { f2bf(a0.x), f2bf(a0.y), f2bf(a0.z), f2bf(a0.w),
                               f2bf(a1.x), f2bf(a1.y), f2bf(a1.z), f2bf(a1.w) };
#pragma unroll
                for (int cf = 0; cf < 4; ++cf)
                    acc[rf][cf] = __builtin_amdgcn_mfma_f32_16x16x32_bf16(
                        af, bfrag[cf][ks], acc[rf][cf], 0, 0, 0);
            }
        }
        // epilogue: C/D layout col = l16, row = 4*lk + reg
#pragma unroll
        for (int rf = 0; rf < 4; ++rf) {
#pragma unroll
            for (int cf = 0; cf < 4; ++cf) {
                int col = 64 * w + 16 * cf + l16;
                int rb  = m0 + 16 * rf + 4 * lk;
#pragma unroll
                for (int r = 0; r < 4; ++r) {
                    int row = rb + r;
                    if (row < N)
                        P[(size_t)row * NCOL + col] = (unsigned short)f2bf(acc[rf][cf][r]);
                }
            }
        }
    }
}

// ---------------------------------------------------------------------------
// Kernel 2: per-edge epilogue on bf16 P. 16 lanes/edge, 16 B/lane gathers.
// ---------------------------------------------------------------------------
__global__ __launch_bounds__(256) void edge_kernel(
    const unsigned short* __restrict__ P,
    const int* __restrict__ ei,     // [2][E] int32
    const float* __restrict__ b1,
    const float* __restrict__ lng,
    const float* __restrict__ lnb,
    const float* __restrict__ W2,
    const float* __restrict__ b2,
    float* __restrict__ out, int E)
{
    const int l16 = threadIdx.x & 15;
    const int c0  = l16 * 8;

    float vb1[8], vg[8], vbt[8], vw2[8];
#pragma unroll
    for (int i = 0; i < 8; i += 4) {
        *(float4*)&vb1[i] = *(const float4*)(b1  + c0 + i);
        *(float4*)&vg[i]  = *(const float4*)(lng + c0 + i);
        *(float4*)&vbt[i] = *(const float4*)(lnb + c0 + i);
        *(float4*)&vw2[i] = *(const float4*)(W2  + c0 + i);
    }
    const float bias2 = b2[0];

    int slot   = blockIdx.x * (blockDim.x >> 4) + (threadIdx.x >> 4);
    int nslots = gridDim.x * (blockDim.x >> 4);

    for (int e = slot; e < E; e += nslots) {
        int src = ei[e];
        int dst = ei[E + e];
        ushort8v ps = *(const ushort8v*)(P + (size_t)src * NCOL + c0);
        ushort8v pd = *(const ushort8v*)(P + (size_t)dst * NCOL + HID + c0);

        float h[8];
        float s = 0.0f, sq = 0.0f;
#pragma unroll
        for (int i = 0; i < 8; ++i) {
            h[i] = bf2f(ps[i]) + bf2f(pd[i]) + vb1[i];
            s  += h[i];
            sq += h[i] * h[i];
        }
#pragma unroll
        for (int m = 8; m >= 1; m >>= 1) {
            s  += __shfl_xor(s,  m, 16);
            sq += __shfl_xor(sq, m, 16);
        }
        float mu  = s * (1.0f / HID);
        float var = sq * (1.0f / HID) - mu * mu;
        float r   = rsqrtf(var + 1e-5f);

        float z = 0.0f;
#pragma unroll
        for (int i = 0; i < 8; ++i) {
            float y = fmaxf(fmaf((h[i] - mu) * r, vg[i], vbt[i]), 0.0f);
            z = fmaf(y, vw2[i], z);
        }
#pragma unroll
        for (int m = 8; m >= 1; m >>= 1) z += __shfl_xor(z, m, 16);

        if (l16 == 0) {
            float zz = z + bias2;
            float wv = 1.0f / (1.0f + expf(-zz));
            if (wv != wv) wv = 0.5f;   // nan_to_num(nan=0.5)
            out[e] = wv;
        }
    }
}

// ---------------------------------------------------------------------------
// Fallback (ws too small): fused per-edge matmul, slow but correct.
// ---------------------------------------------------------------------------
__global__ __launch_bounds__(256) void fused_kernel(
    const float* __restrict__ X,
    const int* __restrict__ ei,
    const float* __restrict__ W1,
    const float* __restrict__ b1,
    const float* __restrict__ lng,
    const float* __restrict__ lnb,
    const float* __restrict__ W2,
    const float* __restrict__ b2,
    float* __restrict__ out, int E)
{
    const int lane = threadIdx.x & 31;
    const int c0   = lane * 4;
    const float4 vb1 = *(const float4*)(b1  + c0);
    const float4 vg  = *(const float4*)(lng + c0);
    const float4 vbt = *(const float4*)(lnb + c0);
    const float4 vw2 = *(const float4*)(W2  + c0);
    const float bias2 = b2[0];

    int slot   = blockIdx.x * (blockDim.x >> 5) + (threadIdx.x >> 5);
    int nslots = gridDim.x * (blockDim.x >> 5);

    for (int e = slot; e < E; e += nslots) {
        int src = ei[e];
        int dst = ei[E + e];
        const float* xs = X + (size_t)src * EMB;
        const float* xd = X + (size_t)dst * EMB;
        float h0 = vb1.x, h1 = vb1.y, h2 = vb1.z, h3 = vb1.w;
        for (int k = 0; k < EMB; ++k) {
            float a  = xs[k];
            float4 w = *(const float4*)(W1 + (size_t)k * HID + c0);
            h0 = fmaf(a, w.x, h0); h1 = fmaf(a, w.y, h1);
            h2 = fmaf(a, w.z, h2); h3 = fmaf(a, w.w, h3);
        }
        for (int k = 0; k < EMB; ++k) {
            float a  = xd[k];
            float4 w = *(const float4*)(W1 + (size_t)(EMB + k) * HID + c0);
            h0 = fmaf(a, w.x, h0); h1 = fmaf(a, w.y, h1);
            h2 = fmaf(a, w.z, h2); h3 = fmaf(a, w.w, h3);
        }
        float s  = h0 + h1 + h2 + h3;
        float sq = h0 * h0 + h1 * h1 + h2 * h2 + h3 * h3;
#pragma unroll
        for (int m = 16; m >= 1; m >>= 1) {
            s  += __shfl_xor(s,  m, 32);
            sq += __shfl_xor(sq, m, 32);
        }
        float mu  = s * (1.0f / HID);
        float var = sq * (1.0f / HID) - mu * mu;
        float r   = rsqrtf(var + 1e-5f);
        float y0 = fmaxf(fmaf((h0 - mu) * r, vg.x, vbt.x), 0.0f);
        float y1 = fmaxf(fmaf((h1 - mu) * r, vg.y, vbt.y), 0.0f);
        float y2 = fmaxf(fmaf((h2 - mu) * r, vg.z, vbt.z), 0.0f);
        float y3 = fmaxf(fmaf((h3 - mu) * r, vg.w, vbt.w), 0.0f);
        float z = y0 * vw2.x + y1 * vw2.y + y2 * vw2.z + y3 * vw2.w;
#pragma unroll
        for (int m = 16; m >= 1; m >>= 1) z += __shfl_xor(z, m, 32);
        if (lane == 0) {
            float zz = z + bias2;
            float wv = 1.0f / (1.0f + expf(-zz));
            if (wv != wv) wv = 0.5f;
            out[e] = wv;
        }
    }
}

extern "C" void kernel_launch(void* const* d_in, const int* in_sizes, int n_in,
                              void* d_out, int out_size, void* d_ws, size_t ws_size,
                              hipStream_t stream) {
    const float* node_emb = (const float*)d_in[0];
    const int*   ei       = (const int*)d_in[1];
    const float* W1       = (const float*)d_in[2];
    const float* b1       = (const float*)d_in[3];
    const float* lng      = (const float*)d_in[4];
    const float* lnb      = (const float*)d_in[5];
    const float* W2       = (const float*)d_in[6];
    const float* b2       = (const float*)d_in[7];
    float* out = (float*)d_out;

    const int N = in_sizes[0] / EMB;   // 100000
    const int E = in_sizes[1] / 2;     // 800000

    const size_t pBytes = (size_t)N * NCOL * sizeof(unsigned short); // 51.2 MB
    const size_t need   = pBytes + (size_t)NCOL * EMB * sizeof(unsigned short);

    if (ws_size >= need) {
        unsigned short* P  = (unsigned short*)d_ws;
        unsigned short* Wt = (unsigned short*)((char*)d_ws + pBytes);

        w_prep<<<(NCOL * EMB) / 256, 256, 0, stream>>>(W1, Wt);

        int nTiles = (N + 63) / 64;
        int gridP  = (nTiles + 1) / 2;          // ~2 tiles per block
        proj_mfma<<<gridP, 256, 0, stream>>>(node_emb, Wt, P, N, nTiles);

        edge_kernel<<<2048, 256, 0, stream>>>(P, ei, b1, lng, lnb, W2, b2, out, E);
    } else {
        fused_kernel<<<2048, 256, 0, stream>>>(node_emb, ei, W1, b1, lng, lnb,
                                               W2, b2, out, E);
    }
}

// Round 5
// 197.965 us; speedup vs baseline: 1.4681x; 1.0312x over previous
//
#include <hip/hip_runtime.h>
#include <hip/hip_bf16.h>
#include <math.h>

#define EMB 128
#define HID 128
#define NCOL 256   // src-proj(128) ++ dst-proj(128)

typedef __attribute__((ext_vector_type(8))) short short8v;   // 8 bf16 = 4 VGPR
typedef __attribute__((ext_vector_type(4))) float f32x4;     // MFMA acc

__device__ __forceinline__ unsigned short f2bf(float f) {
    union { float f; unsigned int u; } v; v.f = f;
    unsigned int r = (v.u + 0x7FFFu + ((v.u >> 16) & 1u)) >> 16;
    return (unsigned short)r;
}

// ---------------------------------------------------------------------------
// Kernel 0: Wt[c][k] (bf16) = combined-W1 transposed:
//   c<128 : W1[k][c] ; c>=128: W1[128+k][c-128]
// ---------------------------------------------------------------------------
__global__ __launch_bounds__(256) void w_prep(
    const float* __restrict__ W1, unsigned short* __restrict__ Wt)
{
    int idx = blockIdx.x * 256 + threadIdx.x;      // 0..32767
    int c = idx >> 7;          // 0..255
    int k = idx & 127;         // 0..127
    float v = W1[(size_t)(k + ((c >> 7) << 7)) * HID + (c & 127)];
    Wt[idx] = f2bf(v);
}

// ---------------------------------------------------------------------------
// Kernel 1: P[n][c] (bf16) via MFMA 16x16x32, operands SWAPPED vs R2:
//   A-operand = Wt rows (M = channel), B-operand = node_emb (N = node).
//   D layout: col(l16) = node, row(4*lk+reg) = channel -> each lane stores
//   4 consecutive channels of one node as one 8B packed store.
// Block = 4 waves; wave w owns channels 64w..64w+63 (A-frags in registers).
// Tile = 16 nodes; grid-stride over tiles.
// ---------------------------------------------------------------------------
__global__ __launch_bounds__(256) void proj_mfma(
    const float* __restrict__ A,          // [N][128] f32
    const unsigned short* __restrict__ Wt,// [256][128] bf16
    unsigned short* __restrict__ P,       // [N][256] bf16
    int N, int nTiles)
{
    const int w    = threadIdx.x >> 6;    // wave 0..3
    const int lane = threadIdx.x & 63;
    const int l16  = lane & 15;
    const int lk   = lane >> 4;           // 0..3

    // W fragments: afrag[cf][ks]; channel c = 64w+16cf+l16, k = 32ks+8lk+i
    short8v afrag[4][4];
#pragma unroll
    for (int cf = 0; cf < 4; ++cf)
#pragma unroll
        for (int ks = 0; ks < 4; ++ks) {
            int c = 64 * w + 16 * cf + l16;
            afrag[cf][ks] = *(const short8v*)(Wt + (size_t)c * EMB + 32 * ks + 8 * lk);
        }

    for (int t = blockIdx.x; t < nTiles; t += gridDim.x) {
        const int n0   = t * 16;
        int node = n0 + l16;
        int nc   = node < N ? node : N - 1;
        const float* ap = A + (size_t)nc * EMB + 8 * lk;

        // B fragments (node data): bf[ks], k = 32ks+8lk+i
        short8v bf[4];
#pragma unroll
        for (int ks = 0; ks < 4; ++ks) {
            float4 a0 = *(const float4*)(ap + 32 * ks);
            float4 a1 = *(const float4*)(ap + 32 * ks + 4);
            short8v f = { (short)f2bf(a0.x), (short)f2bf(a0.y), (short)f2bf(a0.z), (short)f2bf(a0.w),
                          (short)f2bf(a1.x), (short)f2bf(a1.y), (short)f2bf(a1.z), (short)f2bf(a1.w) };
            bf[ks] = f;
        }

        f32x4 acc[4];
#pragma unroll
        for (int cf = 0; cf < 4; ++cf) acc[cf] = (f32x4)0.0f;

#pragma unroll
        for (int ks = 0; ks < 4; ++ks)
#pragma unroll
            for (int cf = 0; cf < 4; ++cf)
                acc[cf] = __builtin_amdgcn_mfma_f32_16x16x32_bf16(
                    afrag[cf][ks], bf[ks], acc[cf], 0, 0, 0);

        // epilogue: node = n0+l16 (col), channels 64w+16cf+4lk+r (row)
        if (node < N) {
            unsigned short* prow = P + (size_t)node * NCOL;
#pragma unroll
            for (int cf = 0; cf < 4; ++cf) {
                unsigned int u0 = (unsigned int)f2bf(acc[cf][0]) |
                                  ((unsigned int)f2bf(acc[cf][1]) << 16);
                unsigned int u1 = (unsigned int)f2bf(acc[cf][2]) |
                                  ((unsigned int)f2bf(acc[cf][3]) << 16);
                uint2 v = make_uint2(u0, u1);
                *(uint2*)(prow + 64 * w + 16 * cf + 4 * lk) = v;
            }
        }
    }
}

// ---------------------------------------------------------------------------
// Kernel 2: per-edge epilogue on bf16 P. 16 lanes/edge, uint4 gathers,
// 1-op/channel bf16 unpack, lean LN apply.
// ---------------------------------------------------------------------------
__global__ __launch_bounds__(256) void edge_kernel(
    const unsigned short* __restrict__ P,
    const int* __restrict__ ei,     // [2][E] int32
    const float* __restrict__ b1,
    const float* __restrict__ lng,
    const float* __restrict__ lnb,
    const float* __restrict__ W2,
    const float* __restrict__ b2,
    float* __restrict__ out, int E)
{
    const int l16 = threadIdx.x & 15;
    const int c0  = l16 * 8;

    float vb1[8], vg[8], vbt[8], vw2[8];
#pragma unroll
    for (int i = 0; i < 8; i += 4) {
        *(float4*)&vb1[i] = *(const float4*)(b1  + c0 + i);
        *(float4*)&vg[i]  = *(const float4*)(lng + c0 + i);
        *(float4*)&vbt[i] = *(const float4*)(lnb + c0 + i);
        *(float4*)&vw2[i] = *(const float4*)(W2  + c0 + i);
    }
    const float bias2 = b2[0];

    int slot   = blockIdx.x * (blockDim.x >> 4) + (threadIdx.x >> 4);
    int nslots = gridDim.x * (blockDim.x >> 4);

    for (int e = slot; e < E; e += nslots) {
        int src = ei[e];
        int dst = ei[E + e];
        uint4 us = *(const uint4*)(P + (size_t)src * NCOL + c0);
        uint4 ud = *(const uint4*)(P + (size_t)dst * NCOL + HID + c0);

        float h[8];
        {
            unsigned int uu[4] = {us.x, us.y, us.z, us.w};
            unsigned int dd[4] = {ud.x, ud.y, ud.z, ud.w};
#pragma unroll
            for (int j = 0; j < 4; ++j) {
                float a0 = __uint_as_float(uu[j] << 16);
                float a1 = __uint_as_float(uu[j] & 0xFFFF0000u);
                float d0 = __uint_as_float(dd[j] << 16);
                float d1 = __uint_as_float(dd[j] & 0xFFFF0000u);
                h[2 * j]     = a0 + d0 + vb1[2 * j];
                h[2 * j + 1] = a1 + d1 + vb1[2 * j + 1];
            }
        }
        float s = 0.0f, sq = 0.0f;
#pragma unroll
        for (int i = 0; i < 8; ++i) {
            s += h[i];
            sq = fmaf(h[i], h[i], sq);
        }
#pragma unroll
        for (int m = 8; m >= 1; m >>= 1) {
            s  += __shfl_xor(s,  m, 16);
            sq += __shfl_xor(sq, m, 16);
        }
        float mu  = s * (1.0f / HID);
        float var = sq * (1.0f / HID) - mu * mu;
        float r   = rsqrtf(var + 1e-5f);
        float nmr = -mu * r;

        float z = 0.0f;
#pragma unroll
        for (int i = 0; i < 8; ++i) {
            float t = fmaf(h[i], r, nmr);
            float y = fmaf(t, vg[i], vbt[i]);
            y = fmaxf(y, 0.0f);
            z = fmaf(y, vw2[i], z);
        }
#pragma unroll
        for (int m = 8; m >= 1; m >>= 1) z += __shfl_xor(z, m, 16);

        if (l16 == 0) {
            float zz = z + bias2;
            float wv = 1.0f / (1.0f + expf(-zz));
            if (wv != wv) wv = 0.5f;   // nan_to_num(nan=0.5)
            out[e] = wv;
        }
    }
}

// ---------------------------------------------------------------------------
// Fallback (ws too small): fused per-edge matmul, slow but correct.
// ---------------------------------------------------------------------------
__global__ __launch_bounds__(256) void fused_kernel(
    const float* __restrict__ X,
    const int* __restrict__ ei,
    const float* __restrict__ W1,
    const float* __restrict__ b1,
    const float* __restrict__ lng,
    const float* __restrict__ lnb,
    const float* __restrict__ W2,
    const float* __restrict__ b2,
    float* __restrict__ out, int E)
{
    const int lane = threadIdx.x & 31;
    const int c0   = lane * 4;
    const float4 vb1 = *(const float4*)(b1  + c0);
    const float4 vg  = *(const float4*)(lng + c0);
    const float4 vbt = *(const float4*)(lnb + c0);
    const float4 vw2 = *(const float4*)(W2  + c0);
    const float bias2 = b2[0];

    int slot   = blockIdx.x * (blockDim.x >> 5) + (threadIdx.x >> 5);
    int nslots = gridDim.x * (blockDim.x >> 5);

    for (int e = slot; e < E; e += nslots) {
        int src = ei[e];
        int dst = ei[E + e];
        const float* xs = X + (size_t)src * EMB;
        const float* xd = X + (size_t)dst * EMB;
        float h0 = vb1.x, h1 = vb1.y, h2 = vb1.z, h3 = vb1.w;
        for (int k = 0; k < EMB; ++k) {
            float a  = xs[k];
            float4 w = *(const float4*)(W1 + (size_t)k * HID + c0);
            h0 = fmaf(a, w.x, h0); h1 = fmaf(a, w.y, h1);
            h2 = fmaf(a, w.z, h2); h3 = fmaf(a, w.w, h3);
        }
        for (int k = 0; k < EMB; ++k) {
            float a  = xd[k];
            float4 w = *(const float4*)(W1 + (size_t)(EMB + k) * HID + c0);
            h0 = fmaf(a, w.x, h0); h1 = fmaf(a, w.y, h1);
            h2 = fmaf(a, w.z, h2); h3 = fmaf(a, w.w, h3);
        }
        float s  = h0 + h1 + h2 + h3;
        float sq = h0 * h0 + h1 * h1 + h2 * h2 + h3 * h3;
#pragma unroll
        for (int m = 16; m >= 1; m >>= 1) {
            s  += __shfl_xor(s,  m, 32);
            sq += __shfl_xor(sq, m, 32);
        }
        float mu  = s * (1.0f / HID);
        float var = sq * (1.0f / HID) - mu * mu;
        float r   = rsqrtf(var + 1e-5f);
        float y0 = fmaxf(fmaf((h0 - mu) * r, vg.x, vbt.x), 0.0f);
        float y1 = fmaxf(fmaf((h1 - mu) * r, vg.y, vbt.y), 0.0f);
        float y2 = fmaxf(fmaf((h2 - mu) * r, vg.z, vbt.z), 0.0f);
        float y3 = fmaxf(fmaf((h3 - mu) * r, vg.w, vbt.w), 0.0f);
        float z = y0 * vw2.x + y1 * vw2.y + y2 * vw2.z + y3 * vw2.w;
#pragma unroll
        for (int m = 16; m >= 1; m >>= 1) z += __shfl_xor(z, m, 32);
        if (lane == 0) {
            float zz = z + bias2;
            float wv = 1.0f / (1.0f + expf(-zz));
            if (wv != wv) wv = 0.5f;
            out[e] = wv;
        }
    }
}

extern "C" void kernel_launch(void* const* d_in, const int* in_sizes, int n_in,
                              void* d_out, int out_size, void* d_ws, size_t ws_size,
                              hipStream_t stream) {
    const float* node_emb = (const float*)d_in[0];
    const int*   ei       = (const int*)d_in[1];
    const float* W1       = (const float*)d_in[2];
    const float* b1       = (const float*)d_in[3];
    const float* lng      = (const float*)d_in[4];
    const float* lnb      = (const float*)d_in[5];
    const float* W2       = (const float*)d_in[6];
    const float* b2       = (const float*)d_in[7];
    float* out = (float*)d_out;

    const int N = in_sizes[0] / EMB;   // 100000
    const int E = in_sizes[1] / 2;     // 800000

    const size_t pBytes = (size_t)N * NCOL * sizeof(unsigned short); // 51.2 MB
    const size_t need   = pBytes + (size_t)NCOL * EMB * sizeof(unsigned short);

    if (ws_size >= need) {
        unsigned short* P  = (unsigned short*)d_ws;
        unsigned short* Wt = (unsigned short*)((char*)d_ws + pBytes);

        w_prep<<<(NCOL * EMB) / 256, 256, 0, stream>>>(W1, Wt);

        int nTiles = (N + 15) / 16;                 // 6250
        int gridP  = nTiles < 2048 ? nTiles : 2048;
        proj_mfma<<<gridP, 256, 0, stream>>>(node_emb, Wt, P, N, nTiles);

        edge_kernel<<<2048, 256, 0, stream>>>(P, ei, b1, lng, lnb, W2, b2, out, E);
    } else {
        fused_kernel<<<2048, 256, 0, stream>>>(node_emb, ei, W1, b1, lng, lnb,
                                               W2, b2, out, E);
    }
}